// Round 15
// baseline (454.061 us; speedup 1.0000x reference)
//
#include <hip/hip_runtime.h>
#include <hip/hip_bf16.h>

#define MPAD   10112    // 79 * 128 (= 158 * 64)
#define NR     10000
#define DM     512
#define DH     2048
#define DIN    2048
#define NCLS   751
#define QKC    262144   // DM*DM

typedef __attribute__((ext_vector_type(8))) short bf16x8;
typedef __attribute__((ext_vector_type(4))) float f32x4;
typedef __attribute__((address_space(3))) void lds_t;
typedef const __attribute__((address_space(1))) void glb_t;

static __device__ __forceinline__ float bf2f(unsigned short s) {
    union { unsigned u; float f; } c; c.u = ((unsigned)s) << 16; return c.f;
}
static __device__ __forceinline__ unsigned short f2bf(float f) {
    __hip_bfloat16 h = __float2bfloat16(f);
    return __builtin_bit_cast(unsigned short, h);
}

// ---------------- fused prep: all weight casts + biases + feats pad, one launch ----------------
// 1-D grid, block ranges:
//  [0,768)        qkv slices (6 x 128 blocks)          f32->bf16
//  [768,1280)     Wred (512)                           f32->bf16
//  [1280,1536)    Wo   (256)                           f32->bf16
//  [1536,2560)    W1   (1024)                          f32->bf16
//  [2560,3584)    W2   (1024)                          f32->bf16
//  [3584,3772)    Wfc' = Wfc*s*bng (188, guarded)      f32->bf16
//  [3772,3784)    catbias (12)
//  [3784,3972)    bnfc_bias (188, wave/row)
//  [3972,14084)   pad_feats (10112)
#define PREP_BLOCKS 14084

static __device__ __forceinline__ void cvt_blk(
    const float* __restrict__ s, unsigned short* __restrict__ d, int rb, int tid)
{
    const int idx = (rb * 256 + tid) * 8;
    float4 a = *(const float4*)(s + idx);
    float4 b = *(const float4*)(s + idx + 4);
    union { unsigned short us[8]; int4 v; } o;
    o.us[0] = f2bf(a.x); o.us[1] = f2bf(a.y); o.us[2] = f2bf(a.z); o.us[3] = f2bf(a.w);
    o.us[4] = f2bf(b.x); o.us[5] = f2bf(b.y); o.us[6] = f2bf(b.z); o.us[7] = f2bf(b.w);
    *(int4*)(d + idx) = o.v;
}

__global__ __launch_bounds__(256) void prep(
    const float* Wq, const float* Wk, const float* Wv,
    const float* Wred, const float* Wo, const float* W1, const float* W2,
    const float* Wfc, const float* bng, const float* bnb,
    const float* bq, const float* bk, const float* bv,
    const float* feats,
    unsigned short* wqkvB, unsigned short* wredB, unsigned short* woB,
    unsigned short* w1B, unsigned short* w2B, unsigned short* wfcB,
    float* biasfc, float* bqkv, unsigned short* h)
{
    int b = blockIdx.x;
    const int tid = threadIdx.x;
    if (b < 768) {
        const int slice = b >> 7, rb = b & 127;
        const float* s;
        switch (slice) {
            case 0: s = Wq; break;        case 1: s = Wk; break;
            case 2: s = Wv; break;        case 3: s = Wq + QKC; break;
            case 4: s = Wk + QKC; break;  default: s = Wv + QKC; break;
        }
        cvt_blk(s, wqkvB + (size_t)slice * QKC, rb, tid);
        return;
    }
    b -= 768;
    if (b < 512)  { cvt_blk(Wred, wredB, b, tid); return; }
    b -= 512;
    if (b < 256)  { cvt_blk(Wo, woB, b, tid); return; }
    b -= 256;
    if (b < 1024) { cvt_blk(W1, w1B, b, tid); return; }
    b -= 1024;
    if (b < 1024) { cvt_blk(W2, w2B, b, tid); return; }
    b -= 1024;
    if (b < 188) {                       // Wfc' = Wfc * rsqrt(1+eps) * bng[d]
        const int idx = (b * 256 + tid) * 8;
        if (idx < NCLS * DM) {
            const float s = rsqrtf(1.f + 1e-5f);
            union { unsigned short us[8]; int4 v; } o;
            #pragma unroll
            for (int j = 0; j < 8; ++j)
                o.us[j] = f2bf(Wfc[idx + j] * s * bng[(idx + j) & (DM - 1)]);
            *(int4*)(wfcB + idx) = o.v;
        }
        return;
    }
    b -= 188;
    if (b < 12) {                        // catbias
        const int t = b * 256 + tid;
        if (t < 2 * 3 * DM) {
            const int l = t / (3 * DM), j = t % (3 * DM);
            float v;
            if (j < DM)          v = bq[l * DM + j];
            else if (j < 2 * DM) v = bk[l * DM + j - DM];
            else                 v = bv[l * DM + j - 2 * DM];
            bqkv[t] = v;
        }
        return;
    }
    b -= 12;
    if (b < 188) {                       // bnfc_bias: wave per class row
        const int row = b * 4 + (tid >> 6);
        const int lane = tid & 63;
        if (row < NCLS) {
            const float* wp = Wfc + (size_t)row * DM + lane * 8;
            const float* bp = bnb + lane * 8;
            float s = 0.f;
            #pragma unroll
            for (int j = 0; j < 8; ++j) s += wp[j] * bp[j];
            #pragma unroll
            for (int off = 32; off > 0; off >>= 1) s += __shfl_xor(s, off, 64);
            if (lane == 0) biasfc[row] = s;
        }
        return;
    }
    b -= 188;
    {                                    // pad_feats
        const size_t t = (size_t)b * 256 + tid;
        const size_t idx = t * 8;
        const int row = (int)(idx / DIN);
        union { unsigned short us[8]; int4 v; } o;
        if (row < NR) {
            float4 a = *(const float4*)(feats + idx);
            float4 c = *(const float4*)(feats + idx + 4);
            o.us[0] = f2bf(a.x); o.us[1] = f2bf(a.y); o.us[2] = f2bf(a.z); o.us[3] = f2bf(a.w);
            o.us[4] = f2bf(c.x); o.us[5] = f2bf(c.y); o.us[6] = f2bf(c.z); o.us[7] = f2bf(c.w);
        } else {
            o.v = (int4){0, 0, 0, 0};
        }
        *(int4*)(h + idx) = o.v;
    }
}

// ---- XCD-aware bijective dispatch swizzle (m204): contiguous chunk per XCD ----
static __device__ __forceinline__ int xcd_swizzle(int nwg) {
    const int d0  = blockIdx.y * gridDim.x + blockIdx.x;
    const int xcd = d0 & 7, dd = d0 >> 3;
    const int qc  = nwg >> 3, rc = nwg & 7;
    return (xcd < rc ? xcd * (qc + 1) : rc * (qc + 1) + (xcd - rc) * qc) + dd;
}

// T2 LDS XOR swizzle (both-sides-or-neither, rule #21):
//   staging: linear LDS dest (global_load_lds), global SOURCE col granule
//            pre-permuted by ((lane&7) ^ srow)  [row&7 == srow for all stripes]
//   read:    slot = (col16) ^ (row&7)  ->  LDS[row][slot] == A[row][col16]

// ---------------- MFMA GEMM, 128x128 tile (single-buffer; qkv / W1) ----------------
// EPI: 0=f32+bias, 1=f32&bf16 dual+bias, 2=bf16+bias, 3=bf16 relu+bias, 4=f32 nobias
template<int EPI, bool GUARD>
__global__ __launch_bounds__(256) void gemm_bt(
    const unsigned short* __restrict__ A,
    const unsigned short* __restrict__ B,
    const float* __restrict__ bias,
    float* __restrict__ outF,
    unsigned short* __restrict__ outH,
    int K, int Nw, int ldc, int Mreal, int Nreal)
{
    __shared__ short As[128 * 64];
    __shared__ short Bs[128 * 64];
    const int tid  = threadIdx.x;
    const int lane = tid & 63;
    const int w    = tid >> 6;
    const int wm   = w >> 1, wn = w & 1;

    const int wgid = xcd_swizzle(gridDim.x * gridDim.y);
    const int bm0 = (wgid / gridDim.x) * 128;
    const int bn0 = (wgid % gridDim.x) * 128;

    f32x4 acc[4][4];
    #pragma unroll
    for (int i = 0; i < 4; ++i)
        #pragma unroll
        for (int j = 0; j < 4; ++j) acc[i][j] = (f32x4){0.f, 0.f, 0.f, 0.f};

    const int srow = lane >> 3;
    const int sslot = ((lane & 7) ^ srow) * 8;
    const int fr   = lane & 15;
    const int fr7  = fr & 7;
    const int c16  = lane >> 4;
    const int nkt  = K >> 6;

    for (int kt = 0; kt < nkt; ++kt) {
        if (kt) __syncthreads();
        #pragma unroll
        for (int c = 0; c < 4; ++c) {
            const int rb = c * 32 + w * 8;
            const int r  = rb + srow;
            const unsigned short* sa = A + (size_t)(bm0 + r) * K + kt * 64 + sslot;
            __builtin_amdgcn_global_load_lds((glb_t*)sa, (lds_t*)&As[rb * 64], 16, 0, 0);
            int br = bn0 + r; if (br >= Nw) br = Nw - 1;
            const unsigned short* sb = B + (size_t)br * K + kt * 64 + sslot;
            __builtin_amdgcn_global_load_lds((glb_t*)sb, (lds_t*)&Bs[rb * 64], 16, 0, 0);
        }
        __syncthreads();
        #pragma unroll
        for (int kk = 0; kk < 64; kk += 32) {
            const int slot = (((kk >> 3) + c16) ^ fr7) * 8;
            bf16x8 av[4], bv[4];
            #pragma unroll
            for (int mi = 0; mi < 4; ++mi)
                av[mi] = *(const bf16x8*)&As[(wm * 64 + mi * 16 + fr) * 64 + slot];
            #pragma unroll
            for (int ni = 0; ni < 4; ++ni)
                bv[ni] = *(const bf16x8*)&Bs[(wn * 64 + ni * 16 + fr) * 64 + slot];
            #pragma unroll
            for (int mi = 0; mi < 4; ++mi)
                #pragma unroll
                for (int ni = 0; ni < 4; ++ni)
                    acc[mi][ni] = __builtin_amdgcn_mfma_f32_16x16x32_bf16(
                        av[mi], bv[ni], acc[mi][ni], 0, 0, 0);
        }
    }

    const int rg = (lane >> 4) * 4;
    #pragma unroll
    for (int mi = 0; mi < 4; ++mi) {
        #pragma unroll
        for (int ni = 0; ni < 4; ++ni) {
            const int col = bn0 + wn * 64 + ni * 16 + fr;
            const int bcol = col < Nw ? col : Nw - 1;
            const float bvv = (EPI == 4) ? 0.f : bias[bcol];
            const f32x4 v = acc[mi][ni];
            #pragma unroll
            for (int j = 0; j < 4; ++j) {
                const int row = bm0 + wm * 64 + mi * 16 + rg + j;
                float val = v[j] + bvv;
                if (EPI == 3) val = fmaxf(val, 0.f);
                if (GUARD && (row >= Mreal || col >= Nreal)) continue;
                const size_t idx = (size_t)row * ldc + col;
                if (EPI == 0 || EPI == 1 || EPI == 4) outF[idx] = val;
                if (EPI == 1 || EPI == 2 || EPI == 3) outH[idx] = f2bf(val);
            }
        }
    }
}

// ---------------- MFMA GEMM, 64x64 tile, T3 2-phase double-buffer ----------------
// Prefetch next K-tile BEFORE compute; counted s_waitcnt vmcnt(4) (4 loads/thread
// in flight) + raw s_barrier -> prefetch spans the barrier (no vmcnt(0) drain).
// 32 KB LDS -> 5 blocks/CU. Numerically identical to single-buffer (round-9-validated).
template<int EPI, bool GUARD>
__global__ __launch_bounds__(256) void gemm_bt64(
    const unsigned short* __restrict__ A,
    const unsigned short* __restrict__ B,
    const float* __restrict__ bias,
    float* __restrict__ outF,
    unsigned short* __restrict__ outH,
    int K, int Nw, int ldc, int Mreal, int Nreal)
{
    __shared__ short As[2][64 * 64];
    __shared__ short Bs[2][64 * 64];
    const int tid  = threadIdx.x;
    const int lane = tid & 63;
    const int w    = tid >> 6;
    const int wm   = w >> 1, wn = w & 1;

    const int wgid = xcd_swizzle(gridDim.x * gridDim.y);
    const int bm0 = (wgid / gridDim.x) * 64;
    const int bn0 = (wgid % gridDim.x) * 64;

    f32x4 acc[2][2];
    #pragma unroll
    for (int i = 0; i < 2; ++i)
        #pragma unroll
        for (int j = 0; j < 2; ++j) acc[i][j] = (f32x4){0.f, 0.f, 0.f, 0.f};

    const int srow = lane >> 3;
    const int sslot = ((lane & 7) ^ srow) * 8;
    const int fr   = lane & 15;
    const int fr7  = fr & 7;
    const int c16  = lane >> 4;
    const int nkt  = K >> 6;

    auto stage = [&](int kt, int buf) {
        #pragma unroll
        for (int c = 0; c < 2; ++c) {
            const int rb = c * 32 + w * 8;
            const int r  = rb + srow;
            const unsigned short* sa = A + (size_t)(bm0 + r) * K + kt * 64 + sslot;
            __builtin_amdgcn_global_load_lds((glb_t*)sa, (lds_t*)&As[buf][rb * 64], 16, 0, 0);
            int br = bn0 + r; if (br >= Nw) br = Nw - 1;
            const unsigned short* sb = B + (size_t)br * K + kt * 64 + sslot;
            __builtin_amdgcn_global_load_lds((glb_t*)sb, (lds_t*)&Bs[buf][rb * 64], 16, 0, 0);
        }
    };

    stage(0, 0);
    for (int kt = 0; kt < nkt; ++kt) {
        const int cur = kt & 1;
        if (kt + 1 < nkt) {
            stage(kt + 1, cur ^ 1);                           // prefetch next tile
            asm volatile("s_waitcnt vmcnt(4)" ::: "memory");  // cur's 4 loads done; 4 in flight
        } else {
            asm volatile("s_waitcnt vmcnt(0)" ::: "memory");
        }
        __builtin_amdgcn_s_barrier();        // raw barrier: prefetch stays in flight
        __builtin_amdgcn_sched_barrier(0);
        #pragma unroll
        for (int kk = 0; kk < 64; kk += 32) {
            const int slot = (((kk >> 3) + c16) ^ fr7) * 8;
            bf16x8 av[2], bv[2];
            #pragma unroll
            for (int mi = 0; mi < 2; ++mi)
                av[mi] = *(const bf16x8*)&As[cur][(wm * 32 + mi * 16 + fr) * 64 + slot];
            #pragma unroll
            for (int ni = 0; ni < 2; ++ni)
                bv[ni] = *(const bf16x8*)&Bs[cur][(wn * 32 + ni * 16 + fr) * 64 + slot];
            #pragma unroll
            for (int mi = 0; mi < 2; ++mi)
                #pragma unroll
                for (int ni = 0; ni < 2; ++ni)
                    acc[mi][ni] = __builtin_amdgcn_mfma_f32_16x16x32_bf16(
                        av[mi], bv[ni], acc[mi][ni], 0, 0, 0);
        }
        asm volatile("s_waitcnt lgkmcnt(0)" ::: "memory");    // my ds_reads landed
        __builtin_amdgcn_sched_barrier(0);
        __builtin_amdgcn_s_barrier();        // all waves done reading cur before re-stage
    }

    const int rg = (lane >> 4) * 4;
    #pragma unroll
    for (int mi = 0; mi < 2; ++mi) {
        #pragma unroll
        for (int ni = 0; ni < 2; ++ni) {
            const int col = bn0 + wn * 32 + ni * 16 + fr;
            const int bcol = col < Nw ? col : Nw - 1;
            const float bvv = (EPI == 4) ? 0.f : bias[bcol];
            const f32x4 v = acc[mi][ni];
            #pragma unroll
            for (int j = 0; j < 4; ++j) {
                const int row = bm0 + wm * 32 + mi * 16 + rg + j;
                float val = v[j] + bvv;
                if (EPI == 3) val = fmaxf(val, 0.f);
                if (GUARD && (row >= Mreal || col >= Nreal)) continue;
                const size_t idx = (size_t)row * ldc + col;
                if (EPI == 0 || EPI == 1 || EPI == 4) outF[idx] = val;
                if (EPI == 1 || EPI == 2 || EPI == 3) outH[idx] = f2bf(val);
            }
        }
    }
}

// ---------------- edge attention: 4 nodes per 256-thread block, 1 wave/node ----------------
__global__ __launch_bounds__(256) void attn_kernel(
    const unsigned short* __restrict__ qkv,
    const int* __restrict__ ei,
    unsigned short* __restrict__ aggb)
{
    const int wid  = threadIdx.x >> 6;
    const int lane = threadIdx.x & 63;
    const int iout = blockIdx.x * 4 + wid;
    const int i    = iout < NR ? iout : NR - 1;
    const int stride = (ei[33] == 0) ? 4 : 2;

    __shared__ int   sr[4][16];
    __shared__ float ssc[4][16 * 8];
    __shared__ float sal[4][16 * 8];

    bf16x8 qv = *(const bf16x8*)(qkv + (size_t)i * 1536 + lane * 8);
    float qf[8];
    #pragma unroll
    for (int j = 0; j < 8; ++j) qf[j] = bf2f((unsigned short)qv[j]);

    if (lane < 16) sr[wid][lane] = ei[((size_t)i * 16 + lane) * stride];
    __syncthreads();

    const int hh = lane >> 3;
    #pragma unroll 4
    for (int e = 0; e < 16; ++e) {
        const int r = sr[wid][e];
        bf16x8 kv = *(const bf16x8*)(qkv + (size_t)r * 1536 + DM + lane * 8);
        float dot = 0.f;
        #pragma unroll
        for (int j = 0; j < 8; ++j) dot += qf[j] * bf2f((unsigned short)kv[j]);
        dot += __shfl_xor(dot, 1, 64);
        dot += __shfl_xor(dot, 2, 64);
        dot += __shfl_xor(dot, 4, 64);
        if ((lane & 7) == 0) ssc[wid][e * 8 + hh] = dot * 0.125f;
    }
    __syncthreads();
    if (lane < 8) {
        float mx = -1e30f;
        for (int e = 0; e < 16; ++e) mx = fmaxf(mx, ssc[wid][e * 8 + lane]);
        float den = 0.f, ex[16];
        for (int e = 0; e < 16; ++e) { ex[e] = expf(ssc[wid][e * 8 + lane] - mx); den += ex[e]; }
        const float inv = 1.f / den;
        for (int e = 0; e < 16; ++e) sal[wid][e * 8 + lane] = ex[e] * inv;
    }
    __syncthreads();
    float accv[8] = {0, 0, 0, 0, 0, 0, 0, 0};
    #pragma unroll 4
    for (int e = 0; e < 16; ++e) {
        const int r = sr[wid][e];
        const float al = sal[wid][e * 8 + hh];
        bf16x8 vv = *(const bf16x8*)(qkv + (size_t)r * 1536 + 2 * DM + lane * 8);
        #pragma unroll
        for (int j = 0; j < 8; ++j) accv[j] += al * bf2f((unsigned short)vv[j]);
    }
    union { unsigned short us[8]; int4 v4; } o;
    if (iout < NR) {
        #pragma unroll
        for (int j = 0; j < 8; ++j) o.us[j] = f2bf(accv[j]);
    } else {
        o.v4 = (int4){0, 0, 0, 0};
    }
    *(int4*)(aggb + (size_t)iout * DM + lane * 8) = o.v4;
}

// ---------------- x = LN(x + f2)*g + be; f2 is bf16; optional f32 feats_out ----------------
__global__ __launch_bounds__(64) void ln_kernel(
    float* __restrict__ x, const unsigned short* __restrict__ f2,
    const float* __restrict__ g, const float* __restrict__ be,
    unsigned short* __restrict__ xb, float* __restrict__ outFeats)
{
    const int row = blockIdx.x;
    const int lane = threadIdx.x;
    float* xp = x + (size_t)row * DM + lane * 8;
    const unsigned short* fp = f2 + (size_t)row * DM + lane * 8;
    float v[8];
    float4 a0 = *(const float4*)xp;
    float4 a1 = *(const float4*)(xp + 4);
    bf16x8 fv = *(const bf16x8*)fp;
    v[0]=a0.x; v[1]=a0.y; v[2]=a0.z; v[3]=a0.w;
    v[4]=a1.x; v[5]=a1.y; v[6]=a1.z; v[7]=a1.w;
    #pragma unroll
    for (int j = 0; j < 8; ++j) v[j] += bf2f((unsigned short)fv[j]);
    float s = 0.f, s2 = 0.f;
    #pragma unroll
    for (int j = 0; j < 8; ++j) { s += v[j]; s2 += v[j] * v[j]; }
    #pragma unroll
    for (int off = 32; off > 0; off >>= 1) {
        s  += __shfl_xor(s, off, 64);
        s2 += __shfl_xor(s2, off, 64);
    }
    const float mean = s * (1.f / DM);
    const float var  = s2 * (1.f / DM) - mean * mean;
    const float rs   = rsqrtf(var + 1e-5f);
    float y[8];
    union { unsigned short us[8]; int4 v4; } o;
    #pragma unroll
    for (int j = 0; j < 8; ++j) {
        const int d = lane * 8 + j;
        y[j] = (v[j] - mean) * rs * g[d] + be[d];
        o.us[j] = f2bf(y[j]);
    }
    float4 w0 = {y[0], y[1], y[2], y[3]}, w1 = {y[4], y[5], y[6], y[7]};
    *(float4*)xp = w0; *(float4*)(xp + 4) = w1;
    *(int4*)(xb + (size_t)row * DM + lane * 8) = o.v4;
    if (outFeats != nullptr && row < NR) {
        float* op = outFeats + (size_t)row * DM + lane * 8;
        *(float4*)op = w0; *(float4*)(op + 4) = w1;
    }
}

extern "C" void kernel_launch(void* const* d_in, const int* in_sizes, int n_in,
                              void* d_out, int out_size, void* d_ws, size_t ws_size,
                              hipStream_t stream)
{
    const float* feats = (const float*)d_in[0];
    const int* ei = (const int*)d_in[1];
    // d_in[2] = edge_attr: unused by the reference
    const float* Wred = (const float*)d_in[3];
    const float* bred = (const float*)d_in[4];
    const float* Wq = (const float*)d_in[5];
    const float* bq = (const float*)d_in[6];
    const float* Wk = (const float*)d_in[7];
    const float* bk = (const float*)d_in[8];
    const float* Wv = (const float*)d_in[9];
    const float* bv = (const float*)d_in[10];
    const float* Wo = (const float*)d_in[11];
    const float* bo = (const float*)d_in[12];
    const float* g1 = (const float*)d_in[13];
    const float* be1 = (const float*)d_in[14];
    const float* W1 = (const float*)d_in[15];
    const float* b1 = (const float*)d_in[16];
    const float* W2 = (const float*)d_in[17];
    const float* b2 = (const float*)d_in[18];
    const float* g2 = (const float*)d_in[19];
    const float* be2 = (const float*)d_in[20];
    const float* bng = (const float*)d_in[21];
    const float* bnb = (const float*)d_in[22];
    const float* Wfc = (const float*)d_in[23];

    char* ws = (char*)d_ws;
    size_t off = 0;
    auto alloc = [&](size_t bytes) {
        void* p = ws + off; off += (bytes + 255) & ~(size_t)255; return p;
    };
    unsigned short* h    = (unsigned short*)alloc((size_t)MPAD * DIN * 2);
    unsigned short* xb   = (unsigned short*)alloc((size_t)MPAD * DM * 2);
    unsigned short* qkvb = (unsigned short*)alloc((size_t)MPAD * 3 * DM * 2);
    unsigned short* aggb = (unsigned short*)alloc((size_t)MPAD * DM * 2);
    unsigned short* tmpH = (unsigned short*)alloc((size_t)MPAD * DM * 2);
    float* x   = (float*)alloc((size_t)MPAD * DM * 4);
    unsigned short* wredB = (unsigned short*)alloc((size_t)DM * DIN * 2);
    unsigned short* wqkvB = (unsigned short*)alloc((size_t)2 * 3 * DM * DM * 2);
    unsigned short* woB   = (unsigned short*)alloc((size_t)2 * DM * DM * 2);
    unsigned short* w1B   = (unsigned short*)alloc((size_t)2 * DH * DM * 2);
    unsigned short* w2B   = (unsigned short*)alloc((size_t)2 * DM * DH * 2);
    unsigned short* wfcB  = (unsigned short*)alloc((size_t)NCLS * DM * 2);
    float* bqkv   = (float*)alloc((size_t)2 * 3 * DM * 4);
    float* biasfc = (float*)alloc((size_t)NCLS * 4);

    const int MT  = MPAD / 128;  // 79
    const int MT2 = MPAD / 64;   // 158

    float* out = (float*)d_out;

    // all prep in one launch
    prep<<<PREP_BLOCKS, 256, 0, stream>>>(
        Wq, Wk, Wv, Wred, Wo, W1, W2, Wfc, bng, bnb, bq, bk, bv, feats,
        wqkvB, wredB, woB, w1B, w2B, wfcB, biasfc, bqkv, h);

    // x, xb = feats @ Wred^T + bred    (64^2 dbuf: grid 8x158)
    gemm_bt64<1, false><<<dim3(DM / 64, MT2), 256, 0, stream>>>(
        h, wredB, bred, x, xb, DIN, DM, DM, MPAD, DM);

    for (int l = 0; l < 2; ++l) {
        const size_t bOff = (size_t)l * DM;
        // qkv = xb @ [Wq;Wk;Wv]^T + [bq;bk;bv]   (N = 1536, 128^2: grid 948)
        gemm_bt<2, false><<<dim3(12, MT), 256, 0, stream>>>(
            xb, wqkvB + (size_t)l * 3 * QKC, bqkv + (size_t)l * 3 * DM,
            nullptr, qkvb, DM, 3 * DM, 3 * DM, MPAD, 3 * DM);
        attn_kernel<<<MPAD / 4, 256, 0, stream>>>(qkvb, ei, aggb);
        // Wo (64^2 dbuf), bf16 out -> tmpH
        gemm_bt64<2, false><<<dim3(DM / 64, MT2), 256, 0, stream>>>(
            aggb, woB + (size_t)l * QKC, bo + bOff, nullptr, tmpH, DM, DM, DM, MPAD, DM);
        ln_kernel<<<MPAD, 64, 0, stream>>>(x, tmpH, g1 + bOff, be1 + bOff, xb, nullptr);
        // W1 (128^2: grid 1264)
        gemm_bt<3, false><<<dim3(16, MT), 256, 0, stream>>>(
            xb, w1B + (size_t)l * DH * DM, b1 + (size_t)l * DH, nullptr, h, DM, DH, DH, MPAD, DH);
        // W2 (64^2 dbuf), bf16 out -> tmpH
        gemm_bt64<2, false><<<dim3(DM / 64, MT2), 256, 0, stream>>>(
            h, w2B + (size_t)l * DM * DH, b2 + bOff, nullptr, tmpH, DH, DM, DM, MPAD, DM);
        ln_kernel<<<MPAD, 64, 0, stream>>>(x, tmpH, g2 + bOff, be2 + bOff, xb,
                                           (l == 1) ? out + (size_t)NR * NCLS : nullptr);
    }

    // logits = bf16(x) @ Wfc'^T + biasfc  (BN folded; 64^2 dbuf, guarded)
    gemm_bt64<0, true><<<dim3((NCLS + 63) / 64, MT2), 256, 0, stream>>>(
        xb, wfcB, biasfc, out, nullptr, DM, NCLS, NCLS, NR, NCLS);

    (void)in_sizes; (void)n_in; (void)out_size; (void)ws_size;
}

// Round 18
// 419.413 us; speedup vs baseline: 1.0826x; 1.0826x over previous
//
#include <hip/hip_runtime.h>
#include <hip/hip_bf16.h>

#define MPAD   10112    // 79 * 128 (= 158 * 64)
#define NR     10000
#define DM     512
#define DH     2048
#define DIN    2048
#define NCLS   751
#define QKC    262144   // DM*DM

typedef __attribute__((ext_vector_type(8))) short bf16x8;
typedef __attribute__((ext_vector_type(4))) float f32x4;
typedef __attribute__((address_space(3))) void lds_t;
typedef const __attribute__((address_space(1))) void glb_t;

static __device__ __forceinline__ float bf2f(unsigned short s) {
    union { unsigned u; float f; } c; c.u = ((unsigned)s) << 16; return c.f;
}
static __device__ __forceinline__ unsigned short f2bf(float f) {
    __hip_bfloat16 h = __float2bfloat16(f);
    return __builtin_bit_cast(unsigned short, h);
}

// ---------------- fused prep: all weight casts + biases + feats pad, one launch ----------------
#define PREP_BLOCKS 14084

static __device__ __forceinline__ void cvt_blk(
    const float* __restrict__ s, unsigned short* __restrict__ d, int rb, int tid)
{
    const int idx = (rb * 256 + tid) * 8;
    float4 a = *(const float4*)(s + idx);
    float4 b = *(const float4*)(s + idx + 4);
    union { unsigned short us[8]; int4 v; } o;
    o.us[0] = f2bf(a.x); o.us[1] = f2bf(a.y); o.us[2] = f2bf(a.z); o.us[3] = f2bf(a.w);
    o.us[4] = f2bf(b.x); o.us[5] = f2bf(b.y); o.us[6] = f2bf(b.z); o.us[7] = f2bf(b.w);
    *(int4*)(d + idx) = o.v;
}

__global__ __launch_bounds__(256) void prep(
    const float* Wq, const float* Wk, const float* Wv,
    const float* Wred, const float* Wo, const float* W1, const float* W2,
    const float* Wfc, const float* bng, const float* bnb,
    const float* bq, const float* bk, const float* bv,
    const float* feats,
    unsigned short* wqkvB, unsigned short* wredB, unsigned short* woB,
    unsigned short* w1B, unsigned short* w2B, unsigned short* wfcB,
    float* biasfc, float* bqkv, unsigned short* h)
{
    int b = blockIdx.x;
    const int tid = threadIdx.x;
    if (b < 768) {
        const int slice = b >> 7, rb = b & 127;
        const float* s;
        switch (slice) {
            case 0: s = Wq; break;        case 1: s = Wk; break;
            case 2: s = Wv; break;        case 3: s = Wq + QKC; break;
            case 4: s = Wk + QKC; break;  default: s = Wv + QKC; break;
        }
        cvt_blk(s, wqkvB + (size_t)slice * QKC, rb, tid);
        return;
    }
    b -= 768;
    if (b < 512)  { cvt_blk(Wred, wredB, b, tid); return; }
    b -= 512;
    if (b < 256)  { cvt_blk(Wo, woB, b, tid); return; }
    b -= 256;
    if (b < 1024) { cvt_blk(W1, w1B, b, tid); return; }
    b -= 1024;
    if (b < 1024) { cvt_blk(W2, w2B, b, tid); return; }
    b -= 1024;
    if (b < 188) {                       // Wfc' = Wfc * rsqrt(1+eps) * bng[d]
        const int idx = (b * 256 + tid) * 8;
        if (idx < NCLS * DM) {
            const float s = rsqrtf(1.f + 1e-5f);
            union { unsigned short us[8]; int4 v; } o;
            #pragma unroll
            for (int j = 0; j < 8; ++j)
                o.us[j] = f2bf(Wfc[idx + j] * s * bng[(idx + j) & (DM - 1)]);
            *(int4*)(wfcB + idx) = o.v;
        }
        return;
    }
    b -= 188;
    if (b < 12) {                        // catbias
        const int t = b * 256 + tid;
        if (t < 2 * 3 * DM) {
            const int l = t / (3 * DM), j = t % (3 * DM);
            float v;
            if (j < DM)          v = bq[l * DM + j];
            else if (j < 2 * DM) v = bk[l * DM + j - DM];
            else                 v = bv[l * DM + j - 2 * DM];
            bqkv[t] = v;
        }
        return;
    }
    b -= 12;
    if (b < 188) {                       // bnfc_bias: wave per class row
        const int row = b * 4 + (tid >> 6);
        const int lane = tid & 63;
        if (row < NCLS) {
            const float* wp = Wfc + (size_t)row * DM + lane * 8;
            const float* bp = bnb + lane * 8;
            float s = 0.f;
            #pragma unroll
            for (int j = 0; j < 8; ++j) s += wp[j] * bp[j];
            #pragma unroll
            for (int off = 32; off > 0; off >>= 1) s += __shfl_xor(s, off, 64);
            if (lane == 0) biasfc[row] = s;
        }
        return;
    }
    b -= 188;
    {                                    // pad_feats
        const size_t t = (size_t)b * 256 + tid;
        const size_t idx = t * 8;
        const int row = (int)(idx / DIN);
        union { unsigned short us[8]; int4 v; } o;
        if (row < NR) {
            float4 a = *(const float4*)(feats + idx);
            float4 c = *(const float4*)(feats + idx + 4);
            o.us[0] = f2bf(a.x); o.us[1] = f2bf(a.y); o.us[2] = f2bf(a.z); o.us[3] = f2bf(a.w);
            o.us[4] = f2bf(c.x); o.us[5] = f2bf(c.y); o.us[6] = f2bf(c.z); o.us[7] = f2bf(c.w);
        } else {
            o.v = (int4){0, 0, 0, 0};
        }
        *(int4*)(h + idx) = o.v;
    }
}

// ---- XCD-aware bijective dispatch swizzle (m204): contiguous chunk per XCD ----
static __device__ __forceinline__ int xcd_swizzle(int nwg) {
    const int d0  = blockIdx.y * gridDim.x + blockIdx.x;
    const int xcd = d0 & 7, dd = d0 >> 3;
    const int qc  = nwg >> 3, rc = nwg & 7;
    return (xcd < rc ? xcd * (qc + 1) : rc * (qc + 1) + (xcd - rc) * qc) + dd;
}

// T2 LDS XOR swizzle (both-sides-or-neither, rule #21):
//   staging: linear LDS dest (global_load_lds), global SOURCE col granule
//            pre-permuted by ((lane&7) ^ srow)  [row&7 == srow for all stripes]
//   read:    slot = (col16) ^ (row&7)  ->  LDS[row][slot] == A[row][col16]

// ---------------- MFMA GEMM, 128x128 tile (single-buffer; qkv / W1) ----------------
// EPI: 0=f32+bias, 1=f32&bf16 dual+bias, 2=bf16+bias, 3=bf16 relu+bias, 4=f32 nobias
template<int EPI, bool GUARD>
__global__ __launch_bounds__(256) void gemm_bt(
    const unsigned short* __restrict__ A,
    const unsigned short* __restrict__ B,
    const float* __restrict__ bias,
    float* __restrict__ outF,
    unsigned short* __restrict__ outH,
    int K, int Nw, int ldc, int Mreal, int Nreal)
{
    __shared__ short As[128 * 64];
    __shared__ short Bs[128 * 64];
    const int tid  = threadIdx.x;
    const int lane = tid & 63;
    const int w    = tid >> 6;
    const int wm   = w >> 1, wn = w & 1;

    const int wgid = xcd_swizzle(gridDim.x * gridDim.y);
    const int bm0 = (wgid / gridDim.x) * 128;
    const int bn0 = (wgid % gridDim.x) * 128;

    f32x4 acc[4][4];
    #pragma unroll
    for (int i = 0; i < 4; ++i)
        #pragma unroll
        for (int j = 0; j < 4; ++j) acc[i][j] = (f32x4){0.f, 0.f, 0.f, 0.f};

    const int srow = lane >> 3;
    const int sslot = ((lane & 7) ^ srow) * 8;
    const int fr   = lane & 15;
    const int fr7  = fr & 7;
    const int c16  = lane >> 4;
    const int nkt  = K >> 6;

    for (int kt = 0; kt < nkt; ++kt) {
        if (kt) __syncthreads();
        #pragma unroll
        for (int c = 0; c < 4; ++c) {
            const int rb = c * 32 + w * 8;
            const int r  = rb + srow;
            const unsigned short* sa = A + (size_t)(bm0 + r) * K + kt * 64 + sslot;
            __builtin_amdgcn_global_load_lds((glb_t*)sa, (lds_t*)&As[rb * 64], 16, 0, 0);
            int br = bn0 + r; if (br >= Nw) br = Nw - 1;
            const unsigned short* sb = B + (size_t)br * K + kt * 64 + sslot;
            __builtin_amdgcn_global_load_lds((glb_t*)sb, (lds_t*)&Bs[rb * 64], 16, 0, 0);
        }
        __syncthreads();
        #pragma unroll
        for (int kk = 0; kk < 64; kk += 32) {
            const int slot = (((kk >> 3) + c16) ^ fr7) * 8;
            bf16x8 av[4], bv[4];
            #pragma unroll
            for (int mi = 0; mi < 4; ++mi)
                av[mi] = *(const bf16x8*)&As[(wm * 64 + mi * 16 + fr) * 64 + slot];
            #pragma unroll
            for (int ni = 0; ni < 4; ++ni)
                bv[ni] = *(const bf16x8*)&Bs[(wn * 64 + ni * 16 + fr) * 64 + slot];
            #pragma unroll
            for (int mi = 0; mi < 4; ++mi)
                #pragma unroll
                for (int ni = 0; ni < 4; ++ni)
                    acc[mi][ni] = __builtin_amdgcn_mfma_f32_16x16x32_bf16(
                        av[mi], bv[ni], acc[mi][ni], 0, 0, 0);
        }
    }

    const int rg = (lane >> 4) * 4;
    #pragma unroll
    for (int mi = 0; mi < 4; ++mi) {
        #pragma unroll
        for (int ni = 0; ni < 4; ++ni) {
            const int col = bn0 + wn * 64 + ni * 16 + fr;
            const int bcol = col < Nw ? col : Nw - 1;
            const float bvv = (EPI == 4) ? 0.f : bias[bcol];
            const f32x4 v = acc[mi][ni];
            #pragma unroll
            for (int j = 0; j < 4; ++j) {
                const int row = bm0 + wm * 64 + mi * 16 + rg + j;
                float val = v[j] + bvv;
                if (EPI == 3) val = fmaxf(val, 0.f);
                if (GUARD && (row >= Mreal || col >= Nreal)) continue;
                const size_t idx = (size_t)row * ldc + col;
                if (EPI == 0 || EPI == 1 || EPI == 4) outF[idx] = val;
                if (EPI == 1 || EPI == 2 || EPI == 3) outH[idx] = f2bf(val);
            }
        }
    }
}

// ---------------- MFMA GEMM, 64x64 tile, single-buffer 16 KB (round-13 version) ----------------
template<int EPI, bool GUARD>
__global__ __launch_bounds__(256) void gemm_bt64(
    const unsigned short* __restrict__ A,
    const unsigned short* __restrict__ B,
    const float* __restrict__ bias,
    float* __restrict__ outF,
    unsigned short* __restrict__ outH,
    int K, int Nw, int ldc, int Mreal, int Nreal)
{
    __shared__ short As[64 * 64];
    __shared__ short Bs[64 * 64];
    const int tid  = threadIdx.x;
    const int lane = tid & 63;
    const int w    = tid >> 6;
    const int wm   = w >> 1, wn = w & 1;

    const int wgid = xcd_swizzle(gridDim.x * gridDim.y);
    const int bm0 = (wgid / gridDim.x) * 64;
    const int bn0 = (wgid % gridDim.x) * 64;

    f32x4 acc[2][2];
    #pragma unroll
    for (int i = 0; i < 2; ++i)
        #pragma unroll
        for (int j = 0; j < 2; ++j) acc[i][j] = (f32x4){0.f, 0.f, 0.f, 0.f};

    const int srow = lane >> 3;
    const int sslot = ((lane & 7) ^ srow) * 8;
    const int fr   = lane & 15;
    const int fr7  = fr & 7;
    const int c16  = lane >> 4;
    const int nkt  = K >> 6;

    for (int kt = 0; kt < nkt; ++kt) {
        if (kt) __syncthreads();
        #pragma unroll
        for (int c = 0; c < 2; ++c) {
            const int rb = c * 32 + w * 8;
            const int r  = rb + srow;
            const unsigned short* sa = A + (size_t)(bm0 + r) * K + kt * 64 + sslot;
            __builtin_amdgcn_global_load_lds((glb_t*)sa, (lds_t*)&As[rb * 64], 16, 0, 0);
            int br = bn0 + r; if (br >= Nw) br = Nw - 1;
            const unsigned short* sb = B + (size_t)br * K + kt * 64 + sslot;
            __builtin_amdgcn_global_load_lds((glb_t*)sb, (lds_t*)&Bs[rb * 64], 16, 0, 0);
        }
        __syncthreads();
        #pragma unroll
        for (int kk = 0; kk < 64; kk += 32) {
            const int slot = (((kk >> 3) + c16) ^ fr7) * 8;
            bf16x8 av[2], bv[2];
            #pragma unroll
            for (int mi = 0; mi < 2; ++mi)
                av[mi] = *(const bf16x8*)&As[(wm * 32 + mi * 16 + fr) * 64 + slot];
            #pragma unroll
            for (int ni = 0; ni < 2; ++ni)
                bv[ni] = *(const bf16x8*)&Bs[(wn * 32 + ni * 16 + fr) * 64 + slot];
            #pragma unroll
            for (int mi = 0; mi < 2; ++mi)
                #pragma unroll
                for (int ni = 0; ni < 2; ++ni)
                    acc[mi][ni] = __builtin_amdgcn_mfma_f32_16x16x32_bf16(
                        av[mi], bv[ni], acc[mi][ni], 0, 0, 0);
        }
    }

    const int rg = (lane >> 4) * 4;
    #pragma unroll
    for (int mi = 0; mi < 2; ++mi) {
        #pragma unroll
        for (int ni = 0; ni < 2; ++ni) {
            const int col = bn0 + wn * 32 + ni * 16 + fr;
            const int bcol = col < Nw ? col : Nw - 1;
            const float bvv = (EPI == 4) ? 0.f : bias[bcol];
            const f32x4 v = acc[mi][ni];
            #pragma unroll
            for (int j = 0; j < 4; ++j) {
                const int row = bm0 + wm * 32 + mi * 16 + rg + j;
                float val = v[j] + bvv;
                if (EPI == 3) val = fmaxf(val, 0.f);
                if (GUARD && (row >= Mreal || col >= Nreal)) continue;
                const size_t idx = (size_t)row * ldc + col;
                if (EPI == 0 || EPI == 1 || EPI == 4) outF[idx] = val;
                if (EPI == 1 || EPI == 2 || EPI == 3) outH[idx] = f2bf(val);
            }
        }
    }
}

// ---------------- edge attention: 4 nodes per 256-thread block, 1 wave/node ----------------
__global__ __launch_bounds__(256) void attn_kernel(
    const unsigned short* __restrict__ qkv,
    const int* __restrict__ ei,
    unsigned short* __restrict__ aggb)
{
    const int wid  = threadIdx.x >> 6;
    const int lane = threadIdx.x & 63;
    const int iout = blockIdx.x * 4 + wid;
    const int i    = iout < NR ? iout : NR - 1;
    const int stride = (ei[33] == 0) ? 4 : 2;

    __shared__ int   sr[4][16];
    __shared__ float ssc[4][16 * 8];
    __shared__ float sal[4][16 * 8];

    bf16x8 qv = *(const bf16x8*)(qkv + (size_t)i * 1536 + lane * 8);
    float qf[8];
    #pragma unroll
    for (int j = 0; j < 8; ++j) qf[j] = bf2f((unsigned short)qv[j]);

    if (lane < 16) sr[wid][lane] = ei[((size_t)i * 16 + lane) * stride];
    __syncthreads();

    const int hh = lane >> 3;
    #pragma unroll 4
    for (int e = 0; e < 16; ++e) {
        const int r = sr[wid][e];
        bf16x8 kv = *(const bf16x8*)(qkv + (size_t)r * 1536 + DM + lane * 8);
        float dot = 0.f;
        #pragma unroll
        for (int j = 0; j < 8; ++j) dot += qf[j] * bf2f((unsigned short)kv[j]);
        dot += __shfl_xor(dot, 1, 64);
        dot += __shfl_xor(dot, 2, 64);
        dot += __shfl_xor(dot, 4, 64);
        if ((lane & 7) == 0) ssc[wid][e * 8 + hh] = dot * 0.125f;
    }
    __syncthreads();
    if (lane < 8) {
        float mx = -1e30f;
        for (int e = 0; e < 16; ++e) mx = fmaxf(mx, ssc[wid][e * 8 + lane]);
        float den = 0.f, ex[16];
        for (int e = 0; e < 16; ++e) { ex[e] = expf(ssc[wid][e * 8 + lane] - mx); den += ex[e]; }
        const float inv = 1.f / den;
        for (int e = 0; e < 16; ++e) sal[wid][e * 8 + lane] = ex[e] * inv;
    }
    __syncthreads();
    float accv[8] = {0, 0, 0, 0, 0, 0, 0, 0};
    #pragma unroll 4
    for (int e = 0; e < 16; ++e) {
        const int r = sr[wid][e];
        const float al = sal[wid][e * 8 + hh];
        bf16x8 vv = *(const bf16x8*)(qkv + (size_t)r * 1536 + 2 * DM + lane * 8);
        #pragma unroll
        for (int j = 0; j < 8; ++j) accv[j] += al * bf2f((unsigned short)vv[j]);
    }
    union { unsigned short us[8]; int4 v4; } o;
    if (iout < NR) {
        #pragma unroll
        for (int j = 0; j < 8; ++j) o.us[j] = f2bf(accv[j]);
    } else {
        o.v4 = (int4){0, 0, 0, 0};
    }
    *(int4*)(aggb + (size_t)iout * DM + lane * 8) = o.v4;
}

// ---------------- x = LN(x + f2)*g + be; f2 is bf16; optional f32 feats_out ----------------
__global__ __launch_bounds__(64) void ln_kernel(
    float* __restrict__ x, const unsigned short* __restrict__ f2,
    const float* __restrict__ g, const float* __restrict__ be,
    unsigned short* __restrict__ xb, float* __restrict__ outFeats)
{
    const int row = blockIdx.x;
    const int lane = threadIdx.x;
    float* xp = x + (size_t)row * DM + lane * 8;
    const unsigned short* fp = f2 + (size_t)row * DM + lane * 8;
    float v[8];
    float4 a0 = *(const float4*)xp;
    float4 a1 = *(const float4*)(xp + 4);
    bf16x8 fv = *(const bf16x8*)fp;
    v[0]=a0.x; v[1]=a0.y; v[2]=a0.z; v[3]=a0.w;
    v[4]=a1.x; v[5]=a1.y; v[6]=a1.z; v[7]=a1.w;
    #pragma unroll
    for (int j = 0; j < 8; ++j) v[j] += bf2f((unsigned short)fv[j]);
    float s = 0.f, s2 = 0.f;
    #pragma unroll
    for (int j = 0; j < 8; ++j) { s += v[j]; s2 += v[j] * v[j]; }
    #pragma unroll
    for (int off = 32; off > 0; off >>= 1) {
        s  += __shfl_xor(s, off, 64);
        s2 += __shfl_xor(s2, off, 64);
    }
    const float mean = s * (1.f / DM);
    const float var  = s2 * (1.f / DM) - mean * mean;
    const float rs   = rsqrtf(var + 1e-5f);
    float y[8];
    union { unsigned short us[8]; int4 v4; } o;
    #pragma unroll
    for (int j = 0; j < 8; ++j) {
        const int d = lane * 8 + j;
        y[j] = (v[j] - mean) * rs * g[d] + be[d];
        o.us[j] = f2bf(y[j]);
    }
    float4 w0 = {y[0], y[1], y[2], y[3]}, w1 = {y[4], y[5], y[6], y[7]};
    *(float4*)xp = w0; *(float4*)(xp + 4) = w1;
    *(int4*)(xb + (size_t)row * DM + lane * 8) = o.v4;
    if (outFeats != nullptr && row < NR) {
        float* op = outFeats + (size_t)row * DM + lane * 8;
        *(float4*)op = w0; *(float4*)(op + 4) = w1;
    }
}

extern "C" void kernel_launch(void* const* d_in, const int* in_sizes, int n_in,
                              void* d_out, int out_size, void* d_ws, size_t ws_size,
                              hipStream_t stream)
{
    const float* feats = (const float*)d_in[0];
    const int* ei = (const int*)d_in[1];
    // d_in[2] = edge_attr: unused by the reference
    const float* Wred = (const float*)d_in[3];
    const float* bred = (const float*)d_in[4];
    const float* Wq = (const float*)d_in[5];
    const float* bq = (const float*)d_in[6];
    const float* Wk = (const float*)d_in[7];
    const float* bk = (const float*)d_in[8];
    const float* Wv = (const float*)d_in[9];
    const float* bv = (const float*)d_in[10];
    const float* Wo = (const float*)d_in[11];
    const float* bo = (const float*)d_in[12];
    const float* g1 = (const float*)d_in[13];
    const float* be1 = (const float*)d_in[14];
    const float* W1 = (const float*)d_in[15];
    const float* b1 = (const float*)d_in[16];
    const float* W2 = (const float*)d_in[17];
    const float* b2 = (const float*)d_in[18];
    const float* g2 = (const float*)d_in[19];
    const float* be2 = (const float*)d_in[20];
    const float* bng = (const float*)d_in[21];
    const float* bnb = (const float*)d_in[22];
    const float* Wfc = (const float*)d_in[23];

    char* ws = (char*)d_ws;
    size_t off = 0;
    auto alloc = [&](size_t bytes) {
        void* p = ws + off; off += (bytes + 255) & ~(size_t)255; return p;
    };
    unsigned short* h    = (unsigned short*)alloc((size_t)MPAD * DIN * 2);
    unsigned short* xb   = (unsigned short*)alloc((size_t)MPAD * DM * 2);
    unsigned short* qkvb = (unsigned short*)alloc((size_t)MPAD * 3 * DM * 2);
    unsigned short* aggb = (unsigned short*)alloc((size_t)MPAD * DM * 2);
    unsigned short* tmpH = (unsigned short*)alloc((size_t)MPAD * DM * 2);
    float* x   = (float*)alloc((size_t)MPAD * DM * 4);
    unsigned short* wredB = (unsigned short*)alloc((size_t)DM * DIN * 2);
    unsigned short* wqkvB = (unsigned short*)alloc((size_t)2 * 3 * DM * DM * 2);
    unsigned short* woB   = (unsigned short*)alloc((size_t)2 * DM * DM * 2);
    unsigned short* w1B   = (unsigned short*)alloc((size_t)2 * DH * DM * 2);
    unsigned short* w2B   = (unsigned short*)alloc((size_t)2 * DM * DH * 2);
    unsigned short* wfcB  = (unsigned short*)alloc((size_t)NCLS * DM * 2);
    float* bqkv   = (float*)alloc((size_t)2 * 3 * DM * 4);
    float* biasfc = (float*)alloc((size_t)NCLS * 4);

    const int MT  = MPAD / 128;  // 79
    const int MT2 = MPAD / 64;   // 158

    float* out = (float*)d_out;

    // all prep in one launch
    prep<<<PREP_BLOCKS, 256, 0, stream>>>(
        Wq, Wk, Wv, Wred, Wo, W1, W2, Wfc, bng, bnb, bq, bk, bv, feats,
        wqkvB, wredB, woB, w1B, w2B, wfcB, biasfc, bqkv, h);

    // x, xb = feats @ Wred^T + bred    (64^2: grid 8x158)
    gemm_bt64<1, false><<<dim3(DM / 64, MT2), 256, 0, stream>>>(
        h, wredB, bred, x, xb, DIN, DM, DM, MPAD, DM);

    for (int l = 0; l < 2; ++l) {
        const size_t bOff = (size_t)l * DM;
        // qkv = xb @ [Wq;Wk;Wv]^T + [bq;bk;bv]   (N = 1536, 128^2: grid 948)
        gemm_bt<2, false><<<dim3(12, MT), 256, 0, stream>>>(
            xb, wqkvB + (size_t)l * 3 * QKC, bqkv + (size_t)l * 3 * DM,
            nullptr, qkvb, DM, 3 * DM, 3 * DM, MPAD, 3 * DM);
        attn_kernel<<<MPAD / 4, 256, 0, stream>>>(qkvb, ei, aggb);
        // Wo (64^2), bf16 out -> tmpH
        gemm_bt64<2, false><<<dim3(DM / 64, MT2), 256, 0, stream>>>(
            aggb, woB + (size_t)l * QKC, bo + bOff, nullptr, tmpH, DM, DM, DM, MPAD, DM);
        ln_kernel<<<MPAD, 64, 0, stream>>>(x, tmpH, g1 + bOff, be1 + bOff, xb, nullptr);
        // W1 (128^2: grid 1264)
        gemm_bt<3, false><<<dim3(16, MT), 256, 0, stream>>>(
            xb, w1B + (size_t)l * DH * DM, b1 + (size_t)l * DH, nullptr, h, DM, DH, DH, MPAD, DH);
        // W2 (64^2), bf16 out -> tmpH
        gemm_bt64<2, false><<<dim3(DM / 64, MT2), 256, 0, stream>>>(
            h, w2B + (size_t)l * DM * DH, b2 + bOff, nullptr, tmpH, DH, DM, DM, MPAD, DM);
        ln_kernel<<<MPAD, 64, 0, stream>>>(x, tmpH, g2 + bOff, be2 + bOff, xb,
                                           (l == 1) ? out + (size_t)NR * NCLS : nullptr);
    }

    // logits = bf16(x) @ Wfc'^T + biasfc  (BN folded; 64^2, guarded)
    gemm_bt64<0, true><<<dim3((NCLS + 63) / 64, MT2), 256, 0, stream>>>(
        xb, wfcB, biasfc, out, nullptr, DM, NCLS, NCLS, NR, NCLS);

    (void)in_sizes; (void)n_in; (void)out_size; (void)ws_size;
}